// Round 1
// baseline (71.219 us; speedup 1.0000x reference)
//
#include <hip/hip_runtime.h>
#include <float.h>

static constexpr int H    = 2048;
static constexpr int Wd   = 2048;
static constexpr int NPIX = H * Wd;

// Monotonic float->uint encoding: preserves total order, so integer
// atomicMin/Max on encodings == float min/max (exact selection).
__device__ __forceinline__ unsigned int enc_f32(float f) {
    unsigned int u = __float_as_uint(f);
    return (u & 0x80000000u) ? ~u : (u | 0x80000000u);
}
__device__ __forceinline__ float dec_f32(unsigned int e) {
    unsigned int u = (e & 0x80000000u) ? (e ^ 0x80000000u) : ~e;
    return __uint_as_float(u);
}

// ws layout (uint32): [0..2] sparse min xyz, [3..5] sparse max xyz,
//                     [6..8] dense  min xyz, [9..11] dense  max xyz
// ws float slot [12]: ratio
__global__ void init_ws_kernel(unsigned int* __restrict__ ws) {
    int t = threadIdx.x;
    if (t < 12) {
        bool is_min = (t % 6) < 3;
        ws[t] = is_min ? 0xFFFFFFFFu : 0u;  // enc(+huge) / enc(-huge) sentinels
    }
}

__global__ __launch_bounds__(256) void reduce_bbox_kernel(
    const float* __restrict__ dense,
    const float* __restrict__ sparse,
    const int*   __restrict__ mask,
    const float* __restrict__ intr,
    unsigned int* __restrict__ ws)
{
    const float fx = intr[0], fy = intr[1], cx = intr[2], cy = intr[3];
    const float inv_fx = 1.0f / fx, inv_fy = 1.0f / fy;

    // local min/max, same slot layout as ws
    float loc[12];
#pragma unroll
    for (int s = 0; s < 12; ++s) loc[s] = ((s % 6) < 3) ? FLT_MAX : -FLT_MAX;

    const float4* d4 = (const float4*)dense;
    const float4* s4 = (const float4*)sparse;
    const int4*   m4 = (const int4*)mask;

    int tid    = blockIdx.x * blockDim.x + threadIdx.x;
    int stride = gridDim.x * blockDim.x;
    const int n4 = NPIX / 4;

    for (int i = tid; i < n4; i += stride) {
        int4   mv = m4[i];
        float4 dv = d4[i];
        float4 sv = s4[i];
        int base = i << 2;                      // 2048 % 4 == 0: row never split
        float yc = (float)(base >> 11) - cy;    // row index - cy
        float xf = (float)(base & 2047);

        const int   mm[4] = { mv.x, mv.y, mv.z, mv.w };
        const float dd[4] = { dv.x, dv.y, dv.z, dv.w };
        const float ss[4] = { sv.x, sv.y, sv.z, sv.w };

#pragma unroll
        for (int j = 0; j < 4; ++j) {
            if (mm[j] != 0) {
                float xc = xf + (float)j - cx;
                float sd = ss[j];
                float de = dd[j];
                float spx = xc * sd * inv_fx;
                float spy = yc * sd * inv_fy;
                float dpx = xc * de * inv_fx;
                float dpy = yc * de * inv_fy;
                loc[0] = fminf(loc[0], spx); loc[3] = fmaxf(loc[3], spx);
                loc[1] = fminf(loc[1], spy); loc[4] = fmaxf(loc[4], spy);
                loc[2] = fminf(loc[2], sd ); loc[5] = fmaxf(loc[5], sd );
                loc[6] = fminf(loc[6], dpx); loc[9]  = fmaxf(loc[9],  dpx);
                loc[7] = fminf(loc[7], dpy); loc[10] = fmaxf(loc[10], dpy);
                loc[8] = fminf(loc[8], de ); loc[11] = fmaxf(loc[11], de );
            }
        }
    }

    // wave-64 butterfly reduction
#pragma unroll
    for (int off = 32; off > 0; off >>= 1) {
#pragma unroll
        for (int s = 0; s < 12; ++s) {
            float o = __shfl_xor(loc[s], off, 64);
            loc[s] = ((s % 6) < 3) ? fminf(loc[s], o) : fmaxf(loc[s], o);
        }
    }

    __shared__ float red[4][12];
    int lane = threadIdx.x & 63;
    int wid  = threadIdx.x >> 6;
    if (lane == 0) {
#pragma unroll
        for (int s = 0; s < 12; ++s) red[wid][s] = loc[s];
    }
    __syncthreads();

    if (threadIdx.x < 12) {
        int s = threadIdx.x;
        bool is_min = (s % 6) < 3;
        float v = red[0][s];
#pragma unroll
        for (int w = 1; w < 4; ++w)
            v = is_min ? fminf(v, red[w][s]) : fmaxf(v, red[w][s]);
        unsigned int e = enc_f32(v);
        if (is_min) atomicMin(&ws[s], e);
        else        atomicMax(&ws[s], e);
    }
}

__global__ void finalize_kernel(const unsigned int* __restrict__ ws,
                                float* __restrict__ ratio,
                                float* __restrict__ out)
{
    if (threadIdx.x == 0 && blockIdx.x == 0) {
        float ss = 0.0f, sd = 0.0f;
#pragma unroll
        for (int c = 0; c < 3; ++c) {
            float a = dec_f32(ws[3 + c]) - dec_f32(ws[c]);      // sparse max-min
            float b = dec_f32(ws[9 + c]) - dec_f32(ws[6 + c]);  // dense  max-min
            ss += a * a;
            sd += b * b;
        }
        ratio[0] = sqrtf(ss) / sqrtf(sd);
        out[NPIX] = 1.0f;  // std
    }
}

__global__ __launch_bounds__(256) void scale_out_kernel(
    const float* __restrict__ dense,
    const float* __restrict__ ratio,
    float* __restrict__ out)
{
    const float r = ratio[0];
    const float4* d4 = (const float4*)dense;
    float4*       o4 = (float4*)out;
    int tid    = blockIdx.x * blockDim.x + threadIdx.x;
    int stride = gridDim.x * blockDim.x;
    const int n4 = NPIX / 4;
    for (int i = tid; i < n4; i += stride) {
        float4 v = d4[i];
        o4[i] = make_float4(v.x * r, v.y * r, v.z * r, v.w * r);
    }
}

extern "C" void kernel_launch(void* const* d_in, const int* in_sizes, int n_in,
                              void* d_out, int out_size, void* d_ws, size_t ws_size,
                              hipStream_t stream) {
    const float* dense  = (const float*)d_in[0];  // depth_estimations
    const float* sparse = (const float*)d_in[1];  // sparse_depths
    const int*   mask   = (const int*)d_in[2];    // sparse_depth_masks
    const float* intr   = (const float*)d_in[3];  // intrinsics

    float*        out   = (float*)d_out;
    unsigned int* ws_u  = (unsigned int*)d_ws;
    float*        ratio = (float*)(ws_u + 12);

    init_ws_kernel<<<1, 64, 0, stream>>>(ws_u);
    reduce_bbox_kernel<<<2048, 256, 0, stream>>>(dense, sparse, mask, intr, ws_u);
    finalize_kernel<<<1, 64, 0, stream>>>(ws_u, ratio, out);
    scale_out_kernel<<<2048, 256, 0, stream>>>(dense, ratio, out);
}

// Round 2
// 49.331 us; speedup vs baseline: 1.4437x; 1.4437x over previous
//
#include <hip/hip_runtime.h>
#include <float.h>

static constexpr int H    = 2048;
static constexpr int Wd   = 2048;
static constexpr int NPIX = H * Wd;
static constexpr int NB   = 2048;   // stage-1 blocks
static constexpr int BT   = 256;    // threads per block
static constexpr int N4   = NPIX / 4;
static constexpr int ITER = N4 / (NB * BT);  // == 2, exact

// ws layout (floats, SoA): ws[s*NB + b] = block b's partial for slot s.
// slots: [0..2] sparse min xyz, [3..5] sparse max xyz,
//        [6..8] dense  min xyz, [9..11] dense  max xyz
// ws[12*NB] = ratio

__global__ __launch_bounds__(BT) void reduce_bbox_kernel(
    const float* __restrict__ dense,
    const float* __restrict__ sparse,
    const int*   __restrict__ mask,
    const float* __restrict__ intr,
    float* __restrict__ ws)
{
    const float fx = intr[0], fy = intr[1], cx = intr[2], cy = intr[3];
    const float inv_fx = 1.0f / fx, inv_fy = 1.0f / fy;

    float loc[12];
#pragma unroll
    for (int s = 0; s < 12; ++s) loc[s] = ((s % 6) < 3) ? FLT_MAX : -FLT_MAX;

    const float4* d4 = (const float4*)dense;
    const float4* s4 = (const float4*)sparse;
    const int4*   m4 = (const int4*)mask;

    const int tid = blockIdx.x * BT + threadIdx.x;

#pragma unroll
    for (int k = 0; k < ITER; ++k) {
        const int i = tid + k * (NB * BT);
        int4   mv = m4[i];
        float4 dv = d4[i];
        float4 sv = s4[i];
        int base = i << 2;                      // 2048 % 4 == 0: row never split
        float yc = (float)(base >> 11) - cy;    // row index - cy
        float xf = (float)(base & 2047);

        const int   mm[4] = { mv.x, mv.y, mv.z, mv.w };
        const float dd[4] = { dv.x, dv.y, dv.z, dv.w };
        const float ss[4] = { sv.x, sv.y, sv.z, sv.w };

#pragma unroll
        for (int j = 0; j < 4; ++j) {
            if (mm[j] != 0) {
                float xc = xf + (float)j - cx;
                float sd = ss[j];
                float de = dd[j];
                float spx = xc * sd * inv_fx;
                float spy = yc * sd * inv_fy;
                float dpx = xc * de * inv_fx;
                float dpy = yc * de * inv_fy;
                loc[0] = fminf(loc[0], spx); loc[3]  = fmaxf(loc[3],  spx);
                loc[1] = fminf(loc[1], spy); loc[4]  = fmaxf(loc[4],  spy);
                loc[2] = fminf(loc[2], sd ); loc[5]  = fmaxf(loc[5],  sd );
                loc[6] = fminf(loc[6], dpx); loc[9]  = fmaxf(loc[9],  dpx);
                loc[7] = fminf(loc[7], dpy); loc[10] = fmaxf(loc[10], dpy);
                loc[8] = fminf(loc[8], de ); loc[11] = fmaxf(loc[11], de );
            }
        }
    }

    // wave-64 butterfly reduction
#pragma unroll
    for (int off = 32; off > 0; off >>= 1) {
#pragma unroll
        for (int s = 0; s < 12; ++s) {
            float o = __shfl_xor(loc[s], off, 64);
            loc[s] = ((s % 6) < 3) ? fminf(loc[s], o) : fmaxf(loc[s], o);
        }
    }

    __shared__ float red[4][12];
    int lane = threadIdx.x & 63;
    int wid  = threadIdx.x >> 6;
    if (lane == 0) {
#pragma unroll
        for (int s = 0; s < 12; ++s) red[wid][s] = loc[s];
    }
    __syncthreads();

    // threads 0..11: combine 4 waves, store partial (NO atomics)
    if (threadIdx.x < 12) {
        int s = threadIdx.x;
        bool is_min = (s % 6) < 3;
        float v = red[0][s];
#pragma unroll
        for (int w = 1; w < 4; ++w)
            v = is_min ? fminf(v, red[w][s]) : fmaxf(v, red[w][s]);
        ws[s * NB + blockIdx.x] = v;
    }
}

// One block: reduce NB partials per slot, compute ratio, write std.
__global__ __launch_bounds__(BT) void finalize_kernel(
    const float* __restrict__ ws_in,
    float* __restrict__ ratio,
    float* __restrict__ out)
{
    float loc[12];
#pragma unroll
    for (int s = 0; s < 12; ++s) {
        bool is_min = (s % 6) < 3;
        float v = is_min ? FLT_MAX : -FLT_MAX;
        for (int b = threadIdx.x; b < NB; b += BT) {
            float p = ws_in[s * NB + b];   // coalesced: consecutive t -> consecutive b
            v = is_min ? fminf(v, p) : fmaxf(v, p);
        }
        loc[s] = v;
    }

#pragma unroll
    for (int off = 32; off > 0; off >>= 1) {
#pragma unroll
        for (int s = 0; s < 12; ++s) {
            float o = __shfl_xor(loc[s], off, 64);
            loc[s] = ((s % 6) < 3) ? fminf(loc[s], o) : fmaxf(loc[s], o);
        }
    }

    __shared__ float red[4][12];
    int lane = threadIdx.x & 63;
    int wid  = threadIdx.x >> 6;
    if (lane == 0) {
#pragma unroll
        for (int s = 0; s < 12; ++s) red[wid][s] = loc[s];
    }
    __syncthreads();

    if (threadIdx.x == 0) {
        float fin[12];
#pragma unroll
        for (int s = 0; s < 12; ++s) {
            bool is_min = (s % 6) < 3;
            float v = red[0][s];
#pragma unroll
            for (int w = 1; w < 4; ++w)
                v = is_min ? fminf(v, red[w][s]) : fmaxf(v, red[w][s]);
            fin[s] = v;
        }
        float ss = 0.0f, sd = 0.0f;
#pragma unroll
        for (int c = 0; c < 3; ++c) {
            float a = fin[3 + c] - fin[c];      // sparse max-min
            float b = fin[9 + c] - fin[6 + c];  // dense  max-min
            ss += a * a;
            sd += b * b;
        }
        ratio[0] = sqrtf(ss) / sqrtf(sd);
        out[NPIX] = 1.0f;  // std
    }
}

__global__ __launch_bounds__(BT) void scale_out_kernel(
    const float* __restrict__ dense,
    const float* __restrict__ ratio,
    float* __restrict__ out)
{
    const float r = ratio[0];
    const float4* d4 = (const float4*)dense;
    float4*       o4 = (float4*)out;
    const int tid = blockIdx.x * BT + threadIdx.x;
#pragma unroll
    for (int k = 0; k < ITER; ++k) {
        const int i = tid + k * (NB * BT);
        float4 v = d4[i];
        o4[i] = make_float4(v.x * r, v.y * r, v.z * r, v.w * r);
    }
}

extern "C" void kernel_launch(void* const* d_in, const int* in_sizes, int n_in,
                              void* d_out, int out_size, void* d_ws, size_t ws_size,
                              hipStream_t stream) {
    const float* dense  = (const float*)d_in[0];  // depth_estimations
    const float* sparse = (const float*)d_in[1];  // sparse_depths
    const int*   mask   = (const int*)d_in[2];    // sparse_depth_masks
    const float* intr   = (const float*)d_in[3];  // intrinsics

    float* out   = (float*)d_out;
    float* ws_f  = (float*)d_ws;
    float* ratio = ws_f + 12 * NB;

    reduce_bbox_kernel<<<NB, BT, 0, stream>>>(dense, sparse, mask, intr, ws_f);
    finalize_kernel<<<1, BT, 0, stream>>>(ws_f, ratio, out);
    scale_out_kernel<<<NB, BT, 0, stream>>>(dense, ratio, out);
}

// Round 3
// 26.706 us; speedup vs baseline: 2.6668x; 1.8472x over previous
//
#include <hip/hip_runtime.h>
#include <float.h>
#include <math.h>

static constexpr int H    = 2048;
static constexpr int Wd   = 2048;
static constexpr int NPIX = H * Wd;
static constexpr int BT   = 256;             // threads per block
static constexpr int N4   = NPIX / 4;

static constexpr int NB1   = 1024;           // stage-1 blocks
static constexpr int ITER1 = N4 / (NB1 * BT);  // == 4, exact

static constexpr int NB2   = 2048;           // stage-2 blocks
static constexpr int ITER2 = N4 / (NB2 * BT);  // == 2, exact

// ws layout (floats, SoA): ws[s*NB1 + b] = block b's partial for slot s.
// slots: [0..2] sparse min {x*z, y*z, z} (UNSCALED by 1/fx,1/fy),
//        [3..5] sparse max, [6..8] dense min, [9..11] dense max

__global__ __launch_bounds__(BT) void reduce_bbox_kernel(
    const float* __restrict__ dense,
    const float* __restrict__ sparse,
    const int*   __restrict__ mask,
    const float* __restrict__ intr,
    float* __restrict__ ws)
{
    const float cx = intr[2], cy = intr[3];
    const float qnan = __uint_as_float(0x7FC00000u);

    float loc[12];
#pragma unroll
    for (int s = 0; s < 12; ++s) loc[s] = ((s % 6) < 3) ? FLT_MAX : -FLT_MAX;

    const float4* d4 = (const float4*)dense;
    const float4* s4 = (const float4*)sparse;
    const int4*   m4 = (const int4*)mask;

    const int tid = blockIdx.x * BT + threadIdx.x;

#pragma unroll
    for (int k = 0; k < ITER1; ++k) {
        const int i = tid + k * (NB1 * BT);
        int4   mv = m4[i];
        float4 dv = d4[i];
        float4 sv = s4[i];
        int base = i << 2;                      // 2048 % 4 == 0: row never split
        float yc = (float)(base >> 11) - cy;    // row index - cy
        float xf = (float)(base & 2047);

        const int   mm[4] = { mv.x, mv.y, mv.z, mv.w };
        const float dd[4] = { dv.x, dv.y, dv.z, dv.w };
        const float ss[4] = { sv.x, sv.y, sv.z, sv.w };

#pragma unroll
        for (int j = 0; j < 4; ++j) {
            // Branchless: NaN sentinel for masked-out pixels. NaN propagates
            // through the muls; v_min_f32/v_max_f32 (IEEE) return the non-NaN
            // operand, so masked-out lanes are no-ops in all 12 min/max.
            float sd = (mm[j] != 0) ? ss[j] : qnan;
            float de = (mm[j] != 0) ? dd[j] : qnan;
            float xc = xf + (float)j - cx;
            float spx = xc * sd;
            float spy = yc * sd;
            float dpx = xc * de;
            float dpy = yc * de;
            loc[0] = fminf(loc[0], spx); loc[3]  = fmaxf(loc[3],  spx);
            loc[1] = fminf(loc[1], spy); loc[4]  = fmaxf(loc[4],  spy);
            loc[2] = fminf(loc[2], sd ); loc[5]  = fmaxf(loc[5],  sd );
            loc[6] = fminf(loc[6], dpx); loc[9]  = fmaxf(loc[9],  dpx);
            loc[7] = fminf(loc[7], dpy); loc[10] = fmaxf(loc[10], dpy);
            loc[8] = fminf(loc[8], de ); loc[11] = fmaxf(loc[11], de );
        }
    }

    // wave-64 butterfly reduction
#pragma unroll
    for (int off = 32; off > 0; off >>= 1) {
#pragma unroll
        for (int s = 0; s < 12; ++s) {
            float o = __shfl_xor(loc[s], off, 64);
            loc[s] = ((s % 6) < 3) ? fminf(loc[s], o) : fmaxf(loc[s], o);
        }
    }

    __shared__ float red[4][12];
    int lane = threadIdx.x & 63;
    int wid  = threadIdx.x >> 6;
    if (lane == 0) {
#pragma unroll
        for (int s = 0; s < 12; ++s) red[wid][s] = loc[s];
    }
    __syncthreads();

    if (threadIdx.x < 12) {
        int s = threadIdx.x;
        bool is_min = (s % 6) < 3;
        float v = red[0][s];
#pragma unroll
        for (int w = 1; w < 4; ++w)
            v = is_min ? fminf(v, red[w][s]) : fmaxf(v, red[w][s]);
        ws[s * NB1 + blockIdx.x] = v;   // plain store, no atomics
    }
}

// Stage 2: every block redundantly reduces the NB1x12 partials (48 KB,
// L2-broadcast), computes ratio, then scales its chunk of dense -> out.
__global__ __launch_bounds__(BT) void finalize_scale_kernel(
    const float* __restrict__ dense,
    const float* __restrict__ intr,
    const float* __restrict__ ws,
    float* __restrict__ out)
{
    float loc[12];
#pragma unroll
    for (int s = 0; s < 12; ++s) loc[s] = ((s % 6) < 3) ? FLT_MAX : -FLT_MAX;

    // coalesced: consecutive threads -> consecutive b
    for (int b = threadIdx.x; b < NB1; b += BT) {
#pragma unroll
        for (int s = 0; s < 12; ++s) {
            float p = ws[s * NB1 + b];
            loc[s] = ((s % 6) < 3) ? fminf(loc[s], p) : fmaxf(loc[s], p);
        }
    }

#pragma unroll
    for (int off = 32; off > 0; off >>= 1) {
#pragma unroll
        for (int s = 0; s < 12; ++s) {
            float o = __shfl_xor(loc[s], off, 64);
            loc[s] = ((s % 6) < 3) ? fminf(loc[s], o) : fmaxf(loc[s], o);
        }
    }

    __shared__ float red[4][12];
    __shared__ float ratio_sh;
    int lane = threadIdx.x & 63;
    int wid  = threadIdx.x >> 6;
    if (lane == 0) {
#pragma unroll
        for (int s = 0; s < 12; ++s) red[wid][s] = loc[s];
    }
    __syncthreads();

    if (threadIdx.x == 0) {
        float fin[12];
#pragma unroll
        for (int s = 0; s < 12; ++s) {
            bool is_min = (s % 6) < 3;
            float v = red[0][s];
#pragma unroll
            for (int w = 1; w < 4; ++w)
                v = is_min ? fminf(v, red[w][s]) : fmaxf(v, red[w][s]);
            fin[s] = v;
        }
        const float inv_fx = 1.0f / intr[0], inv_fy = 1.0f / intr[1];
        float sx = (fin[3]  - fin[0]) * inv_fx;
        float sy = (fin[4]  - fin[1]) * inv_fy;
        float sz =  fin[5]  - fin[2];
        float dx = (fin[9]  - fin[6]) * inv_fx;
        float dy = (fin[10] - fin[7]) * inv_fy;
        float dz =  fin[11] - fin[8];
        ratio_sh = sqrtf(sx*sx + sy*sy + sz*sz) / sqrtf(dx*dx + dy*dy + dz*dz);
    }
    __syncthreads();

    const float r = ratio_sh;
    const float4* dv4 = (const float4*)dense;
    float4*       o4  = (float4*)out;
    const int tid = blockIdx.x * BT + threadIdx.x;
#pragma unroll
    for (int k = 0; k < ITER2; ++k) {
        const int i = tid + k * (NB2 * BT);
        float4 v = dv4[i];
        o4[i] = make_float4(v.x * r, v.y * r, v.z * r, v.w * r);
    }
    if (blockIdx.x == 0 && threadIdx.x == 0) out[NPIX] = 1.0f;  // std
}

extern "C" void kernel_launch(void* const* d_in, const int* in_sizes, int n_in,
                              void* d_out, int out_size, void* d_ws, size_t ws_size,
                              hipStream_t stream) {
    const float* dense  = (const float*)d_in[0];  // depth_estimations
    const float* sparse = (const float*)d_in[1];  // sparse_depths
    const int*   mask   = (const int*)d_in[2];    // sparse_depth_masks
    const float* intr   = (const float*)d_in[3];  // intrinsics

    float* out  = (float*)d_out;
    float* ws_f = (float*)d_ws;

    reduce_bbox_kernel<<<NB1, BT, 0, stream>>>(dense, sparse, mask, intr, ws_f);
    finalize_scale_kernel<<<NB2, BT, 0, stream>>>(dense, intr, ws_f, out);
}